// Round 17
// baseline (1584.035 us; speedup 1.0000x reference)
//
#include <hip/hip_runtime.h>

#define FAST_EXP2(x) __builtin_amdgcn_exp2f(x)
#define FAST_LOG2(x) __builtin_amdgcn_logf(x)
#define FAST_RCP(x)  __builtin_amdgcn_rcpf(x)

// ---------------- workspace layout (float offsets) ----------------
static constexpr size_t S3_SUM=0,   S3_SQ=48;
static constexpr size_t S32A_SUM=96,  S32A_SQ=128;
static constexpr size_t S64A_SUM=160, S64A_SQ=224;
static constexpr size_t S128A_SUM=288,S128A_SQ=416;
static constexpr size_t S128B_SUM=544,S128B_SQ=672;
static constexpr size_t S64B_SUM=800, S64B_SQ=864;
static constexpr size_t S32B_SUM=928, S32B_SQ=960;
static constexpr size_t SPB_=2016, WBAR_=2032, BBAR_=2064;
static constexpr size_t T1_=4096;                    // (8,32,128,128) pre-BN
static constexpr size_t T2_=T1_+4194304;             // (8,64,64,64)
static constexpr size_t T3_=T2_+2097152;             // (8,128,32,32)
static constexpr size_t T4_=T3_+1048576;             // (8,128,32,32)
static constexpr size_t C5_=T4_+1048576;             // (8,64,32,32)
static constexpr size_t U5_=C5_+524288;              // (8,64,64,64)
static constexpr size_t C6_=U5_+2097152;             // (8,32,64,64)
static constexpr size_t U6_=C6_+1048576;             // (8,32,128,128)
static constexpr size_t C7_=U6_+4194304;             // (8,32,128,128)
static constexpr size_t W1S_=C7_+4194304;            // 13824 folded conv1 weights
static constexpr size_t B1S_=W1S_+13824;             // 32 folded conv1 biases
static constexpr size_t PAD_=B1S_+64;                // 48 pad values -B3/A3

// inline BN finalize: raw (sum,sq) -> (scale, shift) for channel c
__device__ inline void bn_ab(const float* __restrict__ sum, const float* __restrict__ sq,
                             const float* __restrict__ g, const float* __restrict__ bb,
                             float invN, int c, float& a, float& b)
{
    float m   = sum[c]*invN;
    float var = fmaxf(sq[c]*invN - m*m, 0.f);
    float inv = rsqrtf(var + 1e-5f);
    a = g[c]*inv;
    b = bb[c] - m*a;
}

// ---------------- branch BN stats over r_k; 1536 blocks ----------------
__global__ __launch_bounds__(256) void k_branch_stats(
    const float* __restrict__ x, const float* __restrict__ n16,
    const float* __restrict__ sig16, const float* __restrict__ b16,
    float* __restrict__ sum, float* __restrict__ sq)
{
    const int c = blockIdx.x >> 9;
    const int chunk = blockIdx.x & 511;
    float nk[16], den[16];
#pragma unroll
    for (int k = 0; k < 16; ++k) { nk[k] = n16[k]; den[k] = powf(sig16[k], nk[k]) + b16[k]; }
    float s[16], q[16];
#pragma unroll
    for (int k = 0; k < 16; ++k) { s[k] = 0.f; q[k] = 0.f; }
    const int per = 1024;
    int start = chunk * per;
    for (int i = start + (int)threadIdx.x; i < start + per; i += 256) {
        int b = i >> 16, hw = i & 65535;
        float xv = x[(size_t)(b*3 + c)*65536 + hw];
        float t = FAST_LOG2(xv);
#pragma unroll
        for (int k = 0; k < 16; ++k) {
            float v = FAST_EXP2(nk[k]*t);
            float r = v * FAST_RCP(v + den[k]);
            s[k] += r; q[k] += r*r;
        }
    }
    __shared__ float red[4][32];
    int lane = threadIdx.x & 63, wid = threadIdx.x >> 6;
#pragma unroll
    for (int k = 0; k < 16; ++k) {
#pragma unroll
        for (int off = 32; off > 0; off >>= 1) {
            s[k] += __shfl_down(s[k], off);
            q[k] += __shfl_down(q[k], off);
        }
    }
    if (lane == 0) {
#pragma unroll
        for (int k = 0; k < 16; ++k) { red[wid][k] = s[k]; red[wid][16+k] = q[k]; }
    }
    __syncthreads();
    if (threadIdx.x < 32) {
        float v = red[0][threadIdx.x] + red[1][threadIdx.x] + red[2][threadIdx.x] + red[3][threadIdx.x];
        int k = threadIdx.x & 15;
        if (threadIdx.x < 16) atomicAdd(&sum[k*3 + c], v);
        else                  atomicAdd(&sq[k*3 + c], v);
    }
}

// ---------------- generic per-channel stats (T4 only) ----------------
__global__ __launch_bounds__(256) void k_stats(
    const float* __restrict__ in, int C, int HW, int nchunks, int per,
    float* __restrict__ sum, float* __restrict__ sq)
{
    int c = blockIdx.x / nchunks;
    int chunk = blockIdx.x - c*nchunks;
    float s = 0.f, q = 0.f;
    int start = chunk * per, end = start + per;
    for (int i = start + (int)threadIdx.x; i < end; i += 256) {
        int b = i / HW, hw = i - b*HW;
        float v = in[((size_t)b*C + c)*HW + hw];
        s += v; q += v*v;
    }
#pragma unroll
    for (int off = 32; off > 0; off >>= 1) { s += __shfl_down(s, off); q += __shfl_down(q, off); }
    __shared__ float ss[4], qq[4];
    int lane = threadIdx.x & 63, wid = threadIdx.x >> 6;
    if (lane == 0) { ss[wid] = s; qq[wid] = q; }
    __syncthreads();
    if (threadIdx.x == 0) {
        atomicAdd(&sum[c], ss[0]+ss[1]+ss[2]+ss[3]);
        atomicAdd(&sq[c],  qq[0]+qq[1]+qq[2]+qq[3]);
    }
}

// ---------------- fill tensor with per-channel bias ----------------
__global__ __launch_bounds__(256) void k_fill(
    float* __restrict__ out, const float* __restrict__ bias, int C, int HW, int total)
{
    int idx = blockIdx.x*256 + threadIdx.x;
    if (idx < total) {
        int c = (idx / HW) % C;
        out[idx] = bias[c];
    }
}

// ---------------- ONE prep kernel: finalize3 + fold w1 + spb/wbar/bbar ----------------
__global__ __launch_bounds__(256) void k_prep_all(
    const float* __restrict__ s3sum, const float* __restrict__ s3sq,
    const float* __restrict__ bn3_g, const float* __restrict__ bn3_b,
    const float* __restrict__ n16, const float* __restrict__ sig16, const float* __restrict__ b16,
    const float* __restrict__ w11, const float* __restrict__ b11,
    const float* __restrict__ w1, const float* __restrict__ b1,
    float* __restrict__ w1s, float* __restrict__ b1s, float* __restrict__ padg,
    float* __restrict__ spb, float* __restrict__ wbar, float* __restrict__ bbar)
{
    __shared__ float a3[48], b3[48];
    int tid = threadIdx.x;
    if (tid < 48) {
        float m   = s3sum[tid]*(1.f/524288.f);
        float var = fmaxf(s3sq[tid]*(1.f/524288.f) - m*m, 0.f);
        float inv = rsqrtf(var + 1e-5f);
        float a   = bn3_g[tid % 3]*inv;
        a3[tid] = a;
        b3[tid] = bn3_b[tid % 3] - m*a;
    }
    if (tid < 16) spb[tid] = powf(sig16[tid], n16[tid]) + b16[tid];
    else if (tid >= 64 && tid < 96) { int j = tid - 64; wbar[j] = (w11[j] + w11[32+j] + w11[64+j]) * (1.f/3.f); }
    else if (tid == 96) bbar[0] = (b11[0] + b11[1] + b11[2]) * (1.f/3.f);
    __syncthreads();
    if (tid < 48) padg[tid] = -b3[tid] * FAST_RCP(a3[tid]);
    for (int t = tid; t < 13824; t += 256) {
        int ci = (t / 9) % 48;
        w1s[t] = w1[t] * a3[ci];
    }
    if (tid < 32) {
        float s = b1[tid];
        const float* wp = w1 + tid*432;
        for (int i = 0; i < 432; ++i) s += wp[i] * b3[i/9];
        b1s[tid] = s;
    }
}

// -------- block-level stats reduce helper, generic COG (redst is [4][2*COG]) --------
template<int COG>
__device__ inline void stats_reduceN(float (&ssum)[COG], float (&ssq)[COG],
                                     float (*redst)[2*COG], int cob,
                                     float* __restrict__ gsum, float* __restrict__ gsq)
{
    int lane = threadIdx.x & 63, wid = threadIdx.x >> 6;
#pragma unroll
    for (int co = 0; co < COG; ++co) {
#pragma unroll
        for (int off = 32; off > 0; off >>= 1) {
            ssum[co] += __shfl_down(ssum[co], off);
            ssq[co]  += __shfl_down(ssq[co],  off);
        }
    }
    if (lane == 0) {
#pragma unroll
        for (int co = 0; co < COG; ++co) { redst[wid][co] = ssum[co]; redst[wid][COG+co] = ssq[co]; }
    }
    __syncthreads();
    if (threadIdx.x < 2*COG) {
        float v = redst[0][threadIdx.x] + redst[1][threadIdx.x] + redst[2][threadIdx.x] + redst[3][threadIdx.x];
        if ((int)threadIdx.x < COG) atomicAdd(&gsum[cob + threadIdx.x], v);
        else                        atomicAdd(&gsq[cob + threadIdx.x - COG], v);
    }
}

// ======== conv1 v4: shared-LDS regen, double-buffered rl, one barrier/curve ========
// (256,2): 128-reg cap; kernel needs 112.
template<int COG>
__global__ __launch_bounds__(256,2) void k_conv1f(
    const float* __restrict__ x,
    const float* __restrict__ n16, const float* __restrict__ spb,
    const float* __restrict__ w1s, const float* __restrict__ b1s,
    const float* __restrict__ padg,
    const float* __restrict__ prelu_a,
    float* __restrict__ out, float* __restrict__ gsum, float* __restrict__ gsq)
{
    const int tx = threadIdx.x & 15, ty = threadIdx.x >> 4;
    const int nco = 32 / COG;
    const int b = blockIdx.z / nco, cob = (blockIdx.z - b*nco)*COG;
    const int x0 = blockIdx.x*32, y0 = blockIdx.y*32;

    __shared__ float wl[COG*48*9];
    __shared__ float rl[2][3*1224];
    __shared__ float nl16[16], dl16[16], padl[48];
    __shared__ float redst[4][2*COG];

    for (int t = threadIdx.x; t < COG*48*9; t += 256) {
        int co = t % COG; int rest = t / COG;
        int kk = rest % 9; int ci = rest / 9;
        wl[t] = w1s[(((size_t)(cob+co))*48 + ci)*9 + kk];
    }
    if (threadIdx.x < 16)       nl16[threadIdx.x]    = n16[threadIdx.x];
    else if (threadIdx.x < 32)  dl16[threadIdx.x-16] = spb[threadIdx.x-16];
    else if (threadIdx.x < 80)  padl[threadIdx.x-32] = padg[threadIdx.x-32];

    float tlr[14];
    int off_[14]; int chpack = 0; int okf = 0;
#pragma unroll
    for (int j = 0; j < 14; ++j) {
        int i = threadIdx.x + 256*j;
        if (i < 3468) {
            int ch = i / 1156, jj = i - ch*1156;
            int rr = jj / 34, cc = jj - rr*34;
            int gy = y0 - 1 + rr, gx = x0 - 1 + cc;
            bool ok = (unsigned)gy < 256u && (unsigned)gx < 256u;
            off_[j] = ch*1224 + rr*36 + cc;
            chpack |= ch << (2*j);
            tlr[j] = 0.f;
            if (ok) {
                okf |= 1 << j;
                tlr[j] = FAST_LOG2(x[((size_t)(b*3+ch))*65536 + gy*256 + gx]);
            }
        } else { off_[j] = 3671; tlr[j] = 0.f; }
    }

    float acc[COG][4];
#pragma unroll
    for (int i = 0; i < COG; ++i)
#pragma unroll
        for (int j = 0; j < 4; ++j) acc[i][j] = 0.f;

    {
        float nk = nl16[0], dk = dl16[0];
#pragma unroll
        for (int j = 0; j < 14; ++j) {
            int ch = (chpack >> (2*j)) & 3;
            float pv = padl[ch];
            float v = FAST_EXP2(nk * tlr[j]);
            float rv = v * FAST_RCP(v + dk);
            rl[0][off_[j]] = ((okf >> j) & 1) ? rv : pv;
        }
    }
    __syncthreads();

#pragma unroll 1
    for (int k = 0; k < 16; ++k) {
        if (k < 15) {
            float nk = nl16[k+1], dk = dl16[k+1];
#pragma unroll
            for (int j = 0; j < 14; ++j) {
                int ch = (chpack >> (2*j)) & 3;
                float pv = padl[(k+1)*3 + ch];
                float v = FAST_EXP2(nk * tlr[j]);
                float rv = v * FAST_RCP(v + dk);
                rl[(k+1)&1][off_[j]] = ((okf >> j) & 1) ? rv : pv;
            }
        }
        const float* rbuf = rl[k&1];
#pragma unroll
        for (int ch = 0; ch < 3; ++ch) {
            const float* tlp = rbuf + ch*1224 + (2*ty)*36 + 2*tx;
            float iv[4][4];
#pragma unroll
            for (int r = 0; r < 4; ++r) {
                float2 a2 = *(const float2*)(tlp + r*36);
                float2 b2 = *(const float2*)(tlp + r*36 + 2);
                iv[r][0]=a2.x; iv[r][1]=a2.y; iv[r][2]=b2.x; iv[r][3]=b2.y;
            }
            const float* wbase = &wl[((k*3+ch)*9)*COG];
#pragma unroll
            for (int kh = 0; kh < 3; ++kh)
#pragma unroll
            for (int kw = 0; kw < 3; ++kw) {
                const int kk = kh*3 + kw;
                float wv[COG];
#pragma unroll
                for (int q = 0; q < COG/4; ++q) {
                    float4 wq = *((const float4*)(wbase + kk*COG) + q);
                    wv[4*q+0]=wq.x; wv[4*q+1]=wq.y; wv[4*q+2]=wq.z; wv[4*q+3]=wq.w;
                }
#pragma unroll
                for (int co = 0; co < COG; ++co)
#pragma unroll
                    for (int py = 0; py < 2; ++py)
#pragma unroll
                        for (int px = 0; px < 2; ++px)
                            acc[co][py*2+px] += wv[co]*iv[py+kh][px+kw];
            }
        }
        __syncthreads();
    }

    float a = __ldg(prelu_a);
    int pyp = (y0 >> 1) + ty, pxp = (x0 >> 1) + tx;
    float ssum[COG], ssq[COG];
#pragma unroll
    for (int co = 0; co < COG; ++co) {
        float bv = b1s[cob + co];
        float v0 = acc[co][0] + bv, v1 = acc[co][1] + bv;
        float v2 = acc[co][2] + bv, v3 = acc[co][3] + bv;
        v0 = v0 >= 0.f ? v0 : a*v0; v1 = v1 >= 0.f ? v1 : a*v1;
        v2 = v2 >= 0.f ? v2 : a*v2; v3 = v3 >= 0.f ? v3 : a*v3;
        float m = fmaxf(fmaxf(v0,v1), fmaxf(v2,v3));
        out[(((size_t)b*32 + cob + co)*128 + pyp)*128 + pxp] = m;
        ssum[co] = m; ssq[co] = m*m;
    }
    __syncthreads();
    stats_reduceN<COG>(ssum, ssq, redst, cob, gsum, gsq);
}

// ======== 32x32-region conv3x3, 2x2 px/thread; CHUNK=4 channels per barrier ========
// launch_bounds by COG: COG<=8 -> (256,4) 64-reg cap; COG=16 -> (256,2) 128-reg cap.
// LDS: wl + 4*4.9KB tile; COG=8/MAXCI<=64 ~29KB (4 blocks), COG=16 ~38KB (2 blocks).
template<int COG, int MAXCI, bool POOL, bool SPLIT, bool STATS>
__global__ __launch_bounds__(256, (COG<=8) ? 4 : 2) void k_conv32(
    const float* __restrict__ in1, int C1,
    const float* __restrict__ sum1, const float* __restrict__ sq1,
    const float* __restrict__ g1, const float* __restrict__ bb1, float invN1,
    const float* __restrict__ in2, int C2,
    const float* __restrict__ sum2, const float* __restrict__ sq2,
    const float* __restrict__ g2, const float* __restrict__ bb2, float invN2,
    const float* __restrict__ w, const float* __restrict__ bias,
    int Cout, int H, int W, const float* __restrict__ prelu_a, int do_prelu,
    int ciN, int nsplit,
    float* __restrict__ out, float* __restrict__ gsum, float* __restrict__ gsq)
{
    const int Cin = C1 + C2;
    const int tx = threadIdx.x & 15, ty = threadIdx.x >> 4;
    const int nco = Cout / COG;
    int z = blockIdx.z;
    const int sp = z % nsplit; z /= nsplit;
    const int b = z / nco, cob = (z - b*nco)*COG;
    const int ci0 = sp * ciN;
    const int x0 = blockIdx.x*32, y0 = blockIdx.y*32;

    __shared__ float wl[COG*MAXCI*9];
    __shared__ float tile[4][34*36];
    __shared__ float redst[4][2*COG];

    for (int t = threadIdx.x; t < COG*ciN*9; t += 256) {
        int co = t % COG; int rest = t / COG;
        int k = rest % 9; int ci = rest / 9;
        wl[t] = w[(((size_t)(cob+co))*Cin + ci0 + ci)*9 + k];
    }

    float acc[COG][4];
#pragma unroll
    for (int i = 0; i < COG; ++i)
#pragma unroll
        for (int j = 0; j < 4; ++j) acc[i][j] = 0.f;

#pragma unroll 1
    for (int cb = 0; cb < ciN; cb += 4) {
#pragma unroll
        for (int sub = 0; sub < 4; ++sub) {
            int ci = ci0 + cb + sub;
            const float* in; int cc; int Cn;
            const float* sm; const float* sqp; const float* gg; const float* bbp; float iN;
            if (ci < C1) { in = in1; cc = ci;      Cn = C1; sm = sum1; sqp = sq1; gg = g1; bbp = bb1; iN = invN1; }
            else         { in = in2; cc = ci - C1; Cn = C2; sm = sum2; sqp = sq2; gg = g2; bbp = bb2; iN = invN2; }
            float scv = 1.f, shv = 0.f;
            if (sm) bn_ab(sm, sqp, gg, bbp, iN, cc, scv, shv);
            const float* base = in + ((size_t)b*Cn + cc)*H*W;
#pragma unroll 1
            for (int i = threadIdx.x; i < 34*34; i += 256) {
                int r = i / 34, c = i - r*34;
                int gy = y0 - 1 + r, gx = x0 - 1 + c;
                float v = 0.f;
                if ((unsigned)gy < (unsigned)H && (unsigned)gx < (unsigned)W)
                    v = base[(size_t)gy*W + gx]*scv + shv;
                tile[sub][r*36 + c] = v;
            }
        }
        __syncthreads();
#pragma unroll
        for (int sub = 0; sub < 4; ++sub) {
            const float* tl = &tile[sub][(2*ty)*36 + 2*tx];
            float iv[4][4];
#pragma unroll
            for (int r = 0; r < 4; ++r) {
                float2 a2 = *(const float2*)(tl + r*36);
                float2 b2 = *(const float2*)(tl + r*36 + 2);
                iv[r][0]=a2.x; iv[r][1]=a2.y; iv[r][2]=b2.x; iv[r][3]=b2.y;
            }
            const float* wbase = &wl[(cb+sub)*9*COG];
#pragma unroll
            for (int kh = 0; kh < 3; ++kh)
#pragma unroll
            for (int kw = 0; kw < 3; ++kw) {
                const int k = kh*3 + kw;
                float wv[COG];
#pragma unroll
                for (int q = 0; q < COG/4; ++q) {
                    float4 wq = *((const float4*)(wbase + k*COG) + q);
                    wv[4*q+0]=wq.x; wv[4*q+1]=wq.y; wv[4*q+2]=wq.z; wv[4*q+3]=wq.w;
                }
#pragma unroll
                for (int co = 0; co < COG; ++co)
#pragma unroll
                    for (int py = 0; py < 2; ++py)
#pragma unroll
                        for (int px = 0; px < 2; ++px)
                            acc[co][py*2+px] += wv[co]*iv[py+kh][px+kw];
            }
        }
        __syncthreads();
    }

    if (SPLIT) {
        int oy = y0 + 2*ty, ox = x0 + 2*tx;
#pragma unroll
        for (int co = 0; co < COG; ++co) {
            float* op = out + (((size_t)b*Cout + cob + co)*H + oy)*W + ox;
            atomicAdd(&op[0],     acc[co][0]);
            atomicAdd(&op[1],     acc[co][1]);
            atomicAdd(&op[W],     acc[co][2]);
            atomicAdd(&op[W + 1], acc[co][3]);
        }
    } else {
        float a = __ldg(prelu_a);
        float ssum[COG], ssq[COG];
        if (POOL) {
            const int Hp = H >> 1, Wp = W >> 1;
            int pyp = (y0 >> 1) + ty, pxp = (x0 >> 1) + tx;
#pragma unroll
            for (int co = 0; co < COG; ++co) {
                float bv = bias[cob + co];
                float v0 = acc[co][0] + bv, v1 = acc[co][1] + bv;
                float v2 = acc[co][2] + bv, v3 = acc[co][3] + bv;
                v0 = v0 >= 0.f ? v0 : a*v0; v1 = v1 >= 0.f ? v1 : a*v1;
                v2 = v2 >= 0.f ? v2 : a*v2; v3 = v3 >= 0.f ? v3 : a*v3;
                float m = fmaxf(fmaxf(v0,v1), fmaxf(v2,v3));
                out[(((size_t)b*Cout + cob + co)*Hp + pyp)*Wp + pxp] = m;
                ssum[co] = m; ssq[co] = m*m;
            }
            if (STATS) stats_reduceN<COG>(ssum, ssq, redst, cob, gsum, gsq);
        } else {
            int oy = y0 + 2*ty, ox = x0 + 2*tx;
#pragma unroll
            for (int co = 0; co < COG; ++co) {
                float bv = bias[cob + co];
                float* op = out + (((size_t)b*Cout + cob + co)*H + oy)*W + ox;
                float v0 = acc[co][0] + bv, v1 = acc[co][1] + bv;
                float v2 = acc[co][2] + bv, v3 = acc[co][3] + bv;
                if (do_prelu) {
                    v0 = v0 >= 0.f ? v0 : a*v0; v1 = v1 >= 0.f ? v1 : a*v1;
                    v2 = v2 >= 0.f ? v2 : a*v2; v3 = v3 >= 0.f ? v3 : a*v3;
                }
                op[0] = v0; op[1] = v1; op[W] = v2; op[W+1] = v3;
                ssum[co] = v0+v1+v2+v3; ssq[co] = v0*v0+v1*v1+v2*v2+v3*v3;
            }
            if (STATS) stats_reduceN<COG>(ssum, ssq, redst, cob, gsum, gsq);
        }
    }
}

// ---------------- bilinear x2 upsample + opt PReLU + fused per-channel stats ----------------
__global__ __launch_bounds__(256) void k_up2(
    const float* __restrict__ in, float* __restrict__ out, int C, int h, int w,
    const float* __restrict__ prelu_a, int do_prelu,
    float* __restrict__ gsum, float* __restrict__ gsq)
{
    int idx = blockIdx.x*256 + threadIdx.x;
    int W2 = 2*w, H2 = 2*h;
    float a = do_prelu ? __ldg(prelu_a) : 0.f;
    int ox = idx % W2; int t = idx / W2; int oy = t % H2; int bc = t / H2;
    float py = ((float)oy * (float)(h-1)) / (float)(2*h - 1);
    int ly = (int)floorf(py); int hy = min(ly+1, h-1); float fy = py - (float)ly;
    float px = ((float)ox * (float)(w-1)) / (float)(2*w - 1);
    int lx = (int)floorf(px); int hx = min(lx+1, w-1); float fx = px - (float)lx;
    const float* p = in + (size_t)bc*h*w;
    float v00 = p[(size_t)ly*w + lx], v01 = p[(size_t)ly*w + hx];
    float v10 = p[(size_t)hy*w + lx], v11 = p[(size_t)hy*w + hx];
    if (do_prelu) {
        v00 = v00 >= 0.f ? v00 : a*v00;
        v01 = v01 >= 0.f ? v01 : a*v01;
        v10 = v10 >= 0.f ? v10 : a*v10;
        v11 = v11 >= 0.f ? v11 : a*v11;
    }
    float v0 = v00*(1.f-fx) + v01*fx;
    float v1 = v10*(1.f-fx) + v11*fx;
    float v = v0*(1.f-fy) + v1*fy;
    out[idx] = v;
    float s = v, q = v*v;
#pragma unroll
    for (int off = 32; off > 0; off >>= 1) { s += __shfl_down(s, off); q += __shfl_down(q, off); }
    __shared__ float ss[4], qq[4];
    int lane = threadIdx.x & 63, wid = threadIdx.x >> 6;
    if (lane == 0) { ss[wid] = s; qq[wid] = q; }
    __syncthreads();
    if (threadIdx.x == 0) {
        int c = bc % C;
        atomicAdd(&gsum[c], ss[0]+ss[1]+ss[2]+ss[3]);
        atomicAdd(&gsq[c],  qq[0]+qq[1]+qq[2]+qq[3]);
    }
}

// ---------------- final ----------------
__global__ __launch_bounds__(256) void k_final(
    const float* __restrict__ c7, const float* __restrict__ x,
    const float* __restrict__ wbar, const float* __restrict__ bbar,
    float* __restrict__ out)
{
    int idx = blockIdx.x*256 + threadIdx.x;
    if (idx >= 8*65536) return;
    int hw = idx & 65535, b = idx >> 16;
    int oy = hw >> 8, ox = hw & 255;
    float py = ((float)oy * 127.f) / 255.f;
    int ly = (int)floorf(py); int hy = min(ly+1, 127); float fy = py - (float)ly;
    float px = ((float)ox * 127.f) / 255.f;
    int lx = (int)floorf(px); int hx = min(lx+1, 127); float fx = px - (float)lx;
    float w00 = (1.f-fy)*(1.f-fx), w01 = (1.f-fy)*fx, w10 = fy*(1.f-fx), w11v = fy*fx;
    const float* base = c7 + (size_t)b*32*16384;
    float accum = bbar[0];
#pragma unroll 8
    for (int j = 0; j < 32; ++j) {
        const float* p = base + (size_t)j*16384;
        float v = p[ly*128 + lx]*w00 + p[ly*128 + hx]*w01 + p[hy*128 + lx]*w10 + p[hy*128 + hx]*w11v;
        float s = FAST_RCP(1.f + __expf(-v));
        accum += wbar[j]*s;
    }
    size_t xb = (size_t)b*3*65536 + hw;
    float x0 = x[xb], x1 = x[xb + 65536], x2 = x[xb + 2*65536];
    float m = (x0 + x1 + x2)*(1.f/3.f) + 1e-6f;
    float sc = accum * FAST_RCP(m);
    out[xb]            = sc*x0;
    out[xb + 65536]    = sc*x1;
    out[xb + 2*65536]  = sc*x2;
}

extern "C" void kernel_launch(void* const* d_in, const int* in_sizes, int n_in,
                              void* d_out, int out_size, void* d_ws, size_t ws_size,
                              hipStream_t stream) {
    const float* x       = (const float*)d_in[0];
    const float* n16     = (const float*)d_in[1];
    const float* sig16   = (const float*)d_in[2];
    const float* bia16   = (const float*)d_in[3];
    const float* prelu_a = (const float*)d_in[4];
    const float* bn3_g   = (const float*)d_in[5];
    const float* bn3_b   = (const float*)d_in[6];
    const float* bn32_g  = (const float*)d_in[7];
    const float* bn32_b  = (const float*)d_in[8];
    const float* bn64_g  = (const float*)d_in[9];
    const float* bn64_b  = (const float*)d_in[10];
    const float* bn128_g = (const float*)d_in[11];
    const float* bn128_b = (const float*)d_in[12];
    const float* w1 = (const float*)d_in[13]; const float* b1 = (const float*)d_in[14];
    const float* w2 = (const float*)d_in[15]; const float* b2 = (const float*)d_in[16];
    const float* w3 = (const float*)d_in[17]; const float* b3 = (const float*)d_in[18];
    const float* w4 = (const float*)d_in[19]; const float* b4 = (const float*)d_in[20];
    const float* w5 = (const float*)d_in[21]; const float* b5 = (const float*)d_in[22];
    const float* w6 = (const float*)d_in[23]; const float* b6 = (const float*)d_in[24];
    const float* w7 = (const float*)d_in[25]; const float* b7 = (const float*)d_in[26];
    const float* w11= (const float*)d_in[27]; const float* b11= (const float*)d_in[28];
    float* ws  = (float*)d_ws;
    float* out = (float*)d_out;

    (void)hipMemsetAsync(d_ws, 0, 4096*sizeof(float), stream);

    k_branch_stats<<<1536, 256, 0, stream>>>(x, n16, sig16, bia16, ws+S3_SUM, ws+S3_SQ);
    k_prep_all<<<1, 256, 0, stream>>>(ws+S3_SUM, ws+S3_SQ, bn3_g, bn3_b, n16, sig16, bia16,
                                      w11, b11, w1, b1,
                                      ws+W1S_, ws+B1S_, ws+PAD_, ws+SPB_, ws+WBAR_, ws+BBAR_);

    // conv1 v4; grid(8,8,32)=2048
    k_conv1f<8><<<dim3(8,8,32), 256, 0, stream>>>(x, n16, ws+SPB_, ws+W1S_, ws+B1S_, ws+PAD_,
                                                  prelu_a, ws+T1_, ws+S32A_SUM, ws+S32A_SQ);

    // conv2 (32->64 @128) + pool + stats; COG=16; grid(4,4,32)=512
    k_conv32<16,32,true,false,true><<<dim3(4,4,32), 256, 0, stream>>>(
        ws+T1_, 32, ws+S32A_SUM, ws+S32A_SQ, bn32_g, bn32_b, 1.f/131072.f,
        nullptr, 0, nullptr, nullptr, nullptr, nullptr, 0.f,
        w2, b2, 64, 128, 128, prelu_a, 1, 32, 1, ws+T2_, ws+S64A_SUM, ws+S64A_SQ);

    // conv3 (64->128 @64) + pool + stats; inline BN from S64A
    k_conv32<8,64,true,false,true><<<dim3(2,2,128), 256, 0, stream>>>(
        ws+T2_, 64, ws+S64A_SUM, ws+S64A_SQ, bn64_g, bn64_b, 1.f/32768.f,
        nullptr, 0, nullptr, nullptr, nullptr, nullptr, 0.f,
        w3, b3, 128, 64, 64, prelu_a, 1, 64, 1, ws+T3_, ws+S128A_SUM, ws+S128A_SQ);

    // conv4 (128->128 @32), NO prelu; splitK=8 -> 1024 blocks, atomic into b4-filled T4
    k_fill<<<4096, 256, 0, stream>>>(ws+T4_, b4, 128, 1024, 1048576);
    k_conv32<8,16,false,true,false><<<dim3(1,1,1024), 256, 0, stream>>>(
        ws+T3_, 128, ws+S128A_SUM, ws+S128A_SQ, bn128_g, bn128_b, 1.f/8192.f,
        nullptr, 0, nullptr, nullptr, nullptr, nullptr, 0.f,
        w4, nullptr, 128, 32, 32, prelu_a, 0, 16, 8, ws+T4_, nullptr, nullptr);
    k_stats<<<512, 256, 0, stream>>>(ws+T4_, 128, 1024, 4, 2048, ws+S128B_SUM, ws+S128B_SQ);

    // conv5 (concat[x4,x3] 256->64 @32); splitK=16 -> 1024 blocks; prelu deferred to up2
    k_fill<<<2048, 256, 0, stream>>>(ws+C5_, b5, 64, 1024, 524288);
    k_conv32<8,16,false,true,false><<<dim3(1,1,1024), 256, 0, stream>>>(
        ws+T4_, 128, ws+S128B_SUM, ws+S128B_SQ, bn128_g, bn128_b, 1.f/8192.f,
        ws+T3_, 128, ws+S128A_SUM, ws+S128A_SQ, bn128_g, bn128_b, 1.f/8192.f,
        w5, nullptr, 64, 32, 32, prelu_a, 0, 16, 16, ws+C5_, nullptr, nullptr);
    k_up2<<<8192, 256, 0, stream>>>(ws+C5_, ws+U5_, 64, 32, 32, prelu_a, 1, ws+S64B_SUM, ws+S64B_SQ);

    // conv6 (concat[x2,x5] 128->32 @64); splitK=8 -> grid(2,2,256)=1024; prelu deferred
    k_fill<<<4096, 256, 0, stream>>>(ws+C6_, b6, 32, 4096, 1048576);
    k_conv32<8,16,false,true,false><<<dim3(2,2,256), 256, 0, stream>>>(
        ws+T2_, 64, ws+S64A_SUM, ws+S64A_SQ, bn64_g, bn64_b, 1.f/32768.f,
        ws+U5_, 64, ws+S64B_SUM, ws+S64B_SQ, bn64_g, bn64_b, 1.f/32768.f,
        w6, nullptr, 32, 64, 64, prelu_a, 0, 16, 8, ws+C6_, nullptr, nullptr);
    k_up2<<<16384, 256, 0, stream>>>(ws+C6_, ws+U6_, 32, 64, 64, prelu_a, 1, ws+S32B_SUM, ws+S32B_SQ);

    // conv7 (concat[x1,x6] 64->32 @128) + prelu; inline BN from S32A and S32B
    k_conv32<8,64,false,false,false><<<dim3(4,4,32), 256, 0, stream>>>(
        ws+T1_, 32, ws+S32A_SUM, ws+S32A_SQ, bn32_g, bn32_b, 1.f/131072.f,
        ws+U6_, 32, ws+S32B_SUM, ws+S32B_SQ, bn32_g, bn32_b, 1.f/131072.f,
        w7, b7, 32, 128, 128, prelu_a, 1, 64, 1, ws+C7_, nullptr, nullptr);

    k_final<<<2048, 256, 0, stream>>>(ws+C7_, x, ws+WBAR_, ws+BBAR_, out);
}

// Round 18
// 1352.383 us; speedup vs baseline: 1.1713x; 1.1713x over previous
//
#include <hip/hip_runtime.h>

#define FAST_EXP2(x) __builtin_amdgcn_exp2f(x)
#define FAST_LOG2(x) __builtin_amdgcn_logf(x)
#define FAST_RCP(x)  __builtin_amdgcn_rcpf(x)

// ---------------- workspace layout (float offsets) ----------------
static constexpr size_t S3_SUM=0,   S3_SQ=48;
static constexpr size_t S32A_SUM=96,  S32A_SQ=128;
static constexpr size_t S64A_SUM=160, S64A_SQ=224;
static constexpr size_t S128A_SUM=288,S128A_SQ=416;
static constexpr size_t S128B_SUM=544,S128B_SQ=672;
static constexpr size_t S64B_SUM=800, S64B_SQ=864;
static constexpr size_t S32B_SUM=928, S32B_SQ=960;
static constexpr size_t SPB_=2016, WBAR_=2032, BBAR_=2064;
static constexpr size_t T1_=4096;                    // (8,32,128,128) pre-BN
static constexpr size_t T2_=T1_+4194304;             // (8,64,64,64)
static constexpr size_t T3_=T2_+2097152;             // (8,128,32,32)
static constexpr size_t T4_=T3_+1048576;             // (8,128,32,32)
static constexpr size_t C5_=T4_+1048576;             // (8,64,32,32)
static constexpr size_t U5_=C5_+524288;              // (8,64,64,64)
static constexpr size_t C6_=U5_+2097152;             // (8,32,64,64)
static constexpr size_t U6_=C6_+1048576;             // (8,32,128,128)
static constexpr size_t C7_=U6_+4194304;             // (8,32,128,128)
static constexpr size_t W1S_=C7_+4194304;            // 13824 folded conv1 weights
static constexpr size_t B1S_=W1S_+13824;             // 32 folded conv1 biases
static constexpr size_t PAD_=B1S_+64;                // 48 pad values -B3/A3

// inline BN finalize: raw (sum,sq) -> (scale, shift) for channel c
__device__ inline void bn_ab(const float* __restrict__ sum, const float* __restrict__ sq,
                             const float* __restrict__ g, const float* __restrict__ bb,
                             float invN, int c, float& a, float& b)
{
    float m   = sum[c]*invN;
    float var = fmaxf(sq[c]*invN - m*m, 0.f);
    float inv = rsqrtf(var + 1e-5f);
    a = g[c]*inv;
    b = bb[c] - m*a;
}

// ---------------- branch BN stats over r_k; 1536 blocks ----------------
__global__ __launch_bounds__(256) void k_branch_stats(
    const float* __restrict__ x, const float* __restrict__ n16,
    const float* __restrict__ sig16, const float* __restrict__ b16,
    float* __restrict__ sum, float* __restrict__ sq)
{
    const int c = blockIdx.x >> 9;
    const int chunk = blockIdx.x & 511;
    float nk[16], den[16];
#pragma unroll
    for (int k = 0; k < 16; ++k) { nk[k] = n16[k]; den[k] = powf(sig16[k], nk[k]) + b16[k]; }
    float s[16], q[16];
#pragma unroll
    for (int k = 0; k < 16; ++k) { s[k] = 0.f; q[k] = 0.f; }
    const int per = 1024;
    int start = chunk * per;
    for (int i = start + (int)threadIdx.x; i < start + per; i += 256) {
        int b = i >> 16, hw = i & 65535;
        float xv = x[(size_t)(b*3 + c)*65536 + hw];
        float t = FAST_LOG2(xv);
#pragma unroll
        for (int k = 0; k < 16; ++k) {
            float v = FAST_EXP2(nk[k]*t);
            float r = v * FAST_RCP(v + den[k]);
            s[k] += r; q[k] += r*r;
        }
    }
    __shared__ float red[4][32];
    int lane = threadIdx.x & 63, wid = threadIdx.x >> 6;
#pragma unroll
    for (int k = 0; k < 16; ++k) {
#pragma unroll
        for (int off = 32; off > 0; off >>= 1) {
            s[k] += __shfl_down(s[k], off);
            q[k] += __shfl_down(q[k], off);
        }
    }
    if (lane == 0) {
#pragma unroll
        for (int k = 0; k < 16; ++k) { red[wid][k] = s[k]; red[wid][16+k] = q[k]; }
    }
    __syncthreads();
    if (threadIdx.x < 32) {
        float v = red[0][threadIdx.x] + red[1][threadIdx.x] + red[2][threadIdx.x] + red[3][threadIdx.x];
        int k = threadIdx.x & 15;
        if (threadIdx.x < 16) atomicAdd(&sum[k*3 + c], v);
        else                  atomicAdd(&sq[k*3 + c], v);
    }
}

// ---------------- generic per-channel stats (T4 only) ----------------
__global__ __launch_bounds__(256) void k_stats(
    const float* __restrict__ in, int C, int HW, int nchunks, int per,
    float* __restrict__ sum, float* __restrict__ sq)
{
    int c = blockIdx.x / nchunks;
    int chunk = blockIdx.x - c*nchunks;
    float s = 0.f, q = 0.f;
    int start = chunk * per, end = start + per;
    for (int i = start + (int)threadIdx.x; i < end; i += 256) {
        int b = i / HW, hw = i - b*HW;
        float v = in[((size_t)b*C + c)*HW + hw];
        s += v; q += v*v;
    }
#pragma unroll
    for (int off = 32; off > 0; off >>= 1) { s += __shfl_down(s, off); q += __shfl_down(q, off); }
    __shared__ float ss[4], qq[4];
    int lane = threadIdx.x & 63, wid = threadIdx.x >> 6;
    if (lane == 0) { ss[wid] = s; qq[wid] = q; }
    __syncthreads();
    if (threadIdx.x == 0) {
        atomicAdd(&sum[c], ss[0]+ss[1]+ss[2]+ss[3]);
        atomicAdd(&sq[c],  qq[0]+qq[1]+qq[2]+qq[3]);
    }
}

// ---------------- fill tensor with per-channel bias ----------------
__global__ __launch_bounds__(256) void k_fill(
    float* __restrict__ out, const float* __restrict__ bias, int C, int HW, int total)
{
    int idx = blockIdx.x*256 + threadIdx.x;
    if (idx < total) {
        int c = (idx / HW) % C;
        out[idx] = bias[c];
    }
}

// ---------------- ONE prep kernel: finalize3 + fold w1 + spb/wbar/bbar ----------------
__global__ __launch_bounds__(256) void k_prep_all(
    const float* __restrict__ s3sum, const float* __restrict__ s3sq,
    const float* __restrict__ bn3_g, const float* __restrict__ bn3_b,
    const float* __restrict__ n16, const float* __restrict__ sig16, const float* __restrict__ b16,
    const float* __restrict__ w11, const float* __restrict__ b11,
    const float* __restrict__ w1, const float* __restrict__ b1,
    float* __restrict__ w1s, float* __restrict__ b1s, float* __restrict__ padg,
    float* __restrict__ spb, float* __restrict__ wbar, float* __restrict__ bbar)
{
    __shared__ float a3[48], b3[48];
    int tid = threadIdx.x;
    if (tid < 48) {
        float m   = s3sum[tid]*(1.f/524288.f);
        float var = fmaxf(s3sq[tid]*(1.f/524288.f) - m*m, 0.f);
        float inv = rsqrtf(var + 1e-5f);
        float a   = bn3_g[tid % 3]*inv;
        a3[tid] = a;
        b3[tid] = bn3_b[tid % 3] - m*a;
    }
    if (tid < 16) spb[tid] = powf(sig16[tid], n16[tid]) + b16[tid];
    else if (tid >= 64 && tid < 96) { int j = tid - 64; wbar[j] = (w11[j] + w11[32+j] + w11[64+j]) * (1.f/3.f); }
    else if (tid == 96) bbar[0] = (b11[0] + b11[1] + b11[2]) * (1.f/3.f);
    __syncthreads();
    if (tid < 48) padg[tid] = -b3[tid] * FAST_RCP(a3[tid]);
    for (int t = tid; t < 13824; t += 256) {
        int ci = (t / 9) % 48;
        w1s[t] = w1[t] * a3[ci];
    }
    if (tid < 32) {
        float s = b1[tid];
        const float* wp = w1 + tid*432;
        for (int i = 0; i < 432; ++i) s += wp[i] * b3[i/9];
        b1s[tid] = s;
    }
}

// -------- block-level stats reduce helper, generic COG (redst is [4][2*COG]) --------
template<int COG>
__device__ inline void stats_reduceN(float (&ssum)[COG], float (&ssq)[COG],
                                     float (*redst)[2*COG], int cob,
                                     float* __restrict__ gsum, float* __restrict__ gsq)
{
    int lane = threadIdx.x & 63, wid = threadIdx.x >> 6;
#pragma unroll
    for (int co = 0; co < COG; ++co) {
#pragma unroll
        for (int off = 32; off > 0; off >>= 1) {
            ssum[co] += __shfl_down(ssum[co], off);
            ssq[co]  += __shfl_down(ssq[co],  off);
        }
    }
    if (lane == 0) {
#pragma unroll
        for (int co = 0; co < COG; ++co) { redst[wid][co] = ssum[co]; redst[wid][COG+co] = ssq[co]; }
    }
    __syncthreads();
    if (threadIdx.x < 2*COG) {
        float v = redst[0][threadIdx.x] + redst[1][threadIdx.x] + redst[2][threadIdx.x] + redst[3][threadIdx.x];
        if ((int)threadIdx.x < COG) atomicAdd(&gsum[cob + threadIdx.x], v);
        else                        atomicAdd(&gsq[cob + threadIdx.x - COG], v);
    }
}

// ======== conv1 v4: shared-LDS regen, double-buffered rl, one barrier/curve ========
// (256,2): 128-reg cap; kernel needs 112.
template<int COG>
__global__ __launch_bounds__(256,2) void k_conv1f(
    const float* __restrict__ x,
    const float* __restrict__ n16, const float* __restrict__ spb,
    const float* __restrict__ w1s, const float* __restrict__ b1s,
    const float* __restrict__ padg,
    const float* __restrict__ prelu_a,
    float* __restrict__ out, float* __restrict__ gsum, float* __restrict__ gsq)
{
    const int tx = threadIdx.x & 15, ty = threadIdx.x >> 4;
    const int nco = 32 / COG;
    const int b = blockIdx.z / nco, cob = (blockIdx.z - b*nco)*COG;
    const int x0 = blockIdx.x*32, y0 = blockIdx.y*32;

    __shared__ float wl[COG*48*9];
    __shared__ float rl[2][3*1224];
    __shared__ float nl16[16], dl16[16], padl[48];
    __shared__ float redst[4][2*COG];

    for (int t = threadIdx.x; t < COG*48*9; t += 256) {
        int co = t % COG; int rest = t / COG;
        int kk = rest % 9; int ci = rest / 9;
        wl[t] = w1s[(((size_t)(cob+co))*48 + ci)*9 + kk];
    }
    if (threadIdx.x < 16)       nl16[threadIdx.x]    = n16[threadIdx.x];
    else if (threadIdx.x < 32)  dl16[threadIdx.x-16] = spb[threadIdx.x-16];
    else if (threadIdx.x < 80)  padl[threadIdx.x-32] = padg[threadIdx.x-32];

    float tlr[14];
    int off_[14]; int chpack = 0; int okf = 0;
#pragma unroll
    for (int j = 0; j < 14; ++j) {
        int i = threadIdx.x + 256*j;
        if (i < 3468) {
            int ch = i / 1156, jj = i - ch*1156;
            int rr = jj / 34, cc = jj - rr*34;
            int gy = y0 - 1 + rr, gx = x0 - 1 + cc;
            bool ok = (unsigned)gy < 256u && (unsigned)gx < 256u;
            off_[j] = ch*1224 + rr*36 + cc;
            chpack |= ch << (2*j);
            tlr[j] = 0.f;
            if (ok) {
                okf |= 1 << j;
                tlr[j] = FAST_LOG2(x[((size_t)(b*3+ch))*65536 + gy*256 + gx]);
            }
        } else { off_[j] = 3671; tlr[j] = 0.f; }
    }

    float acc[COG][4];
#pragma unroll
    for (int i = 0; i < COG; ++i)
#pragma unroll
        for (int j = 0; j < 4; ++j) acc[i][j] = 0.f;

    {
        float nk = nl16[0], dk = dl16[0];
#pragma unroll
        for (int j = 0; j < 14; ++j) {
            int ch = (chpack >> (2*j)) & 3;
            float pv = padl[ch];
            float v = FAST_EXP2(nk * tlr[j]);
            float rv = v * FAST_RCP(v + dk);
            rl[0][off_[j]] = ((okf >> j) & 1) ? rv : pv;
        }
    }
    __syncthreads();

#pragma unroll 1
    for (int k = 0; k < 16; ++k) {
        if (k < 15) {
            float nk = nl16[k+1], dk = dl16[k+1];
#pragma unroll
            for (int j = 0; j < 14; ++j) {
                int ch = (chpack >> (2*j)) & 3;
                float pv = padl[(k+1)*3 + ch];
                float v = FAST_EXP2(nk * tlr[j]);
                float rv = v * FAST_RCP(v + dk);
                rl[(k+1)&1][off_[j]] = ((okf >> j) & 1) ? rv : pv;
            }
        }
        const float* rbuf = rl[k&1];
#pragma unroll
        for (int ch = 0; ch < 3; ++ch) {
            const float* tlp = rbuf + ch*1224 + (2*ty)*36 + 2*tx;
            float iv[4][4];
#pragma unroll
            for (int r = 0; r < 4; ++r) {
                float2 a2 = *(const float2*)(tlp + r*36);
                float2 b2 = *(const float2*)(tlp + r*36 + 2);
                iv[r][0]=a2.x; iv[r][1]=a2.y; iv[r][2]=b2.x; iv[r][3]=b2.y;
            }
            const float* wbase = &wl[((k*3+ch)*9)*COG];
#pragma unroll
            for (int kh = 0; kh < 3; ++kh)
#pragma unroll
            for (int kw = 0; kw < 3; ++kw) {
                const int kk = kh*3 + kw;
                float wv[COG];
#pragma unroll
                for (int q = 0; q < COG/4; ++q) {
                    float4 wq = *((const float4*)(wbase + kk*COG) + q);
                    wv[4*q+0]=wq.x; wv[4*q+1]=wq.y; wv[4*q+2]=wq.z; wv[4*q+3]=wq.w;
                }
#pragma unroll
                for (int co = 0; co < COG; ++co)
#pragma unroll
                    for (int py = 0; py < 2; ++py)
#pragma unroll
                        for (int px = 0; px < 2; ++px)
                            acc[co][py*2+px] += wv[co]*iv[py+kh][px+kw];
            }
        }
        __syncthreads();
    }

    float a = __ldg(prelu_a);
    int pyp = (y0 >> 1) + ty, pxp = (x0 >> 1) + tx;
    float ssum[COG], ssq[COG];
#pragma unroll
    for (int co = 0; co < COG; ++co) {
        float bv = b1s[cob + co];
        float v0 = acc[co][0] + bv, v1 = acc[co][1] + bv;
        float v2 = acc[co][2] + bv, v3 = acc[co][3] + bv;
        v0 = v0 >= 0.f ? v0 : a*v0; v1 = v1 >= 0.f ? v1 : a*v1;
        v2 = v2 >= 0.f ? v2 : a*v2; v3 = v3 >= 0.f ? v3 : a*v3;
        float m = fmaxf(fmaxf(v0,v1), fmaxf(v2,v3));
        out[(((size_t)b*32 + cob + co)*128 + pyp)*128 + pxp] = m;
        ssum[co] = m; ssq[co] = m*m;
    }
    __syncthreads();
    stats_reduceN<COG>(ssum, ssq, redst, cob, gsum, gsq);
}

// ======== 32x32-region conv3x3, 2x2 px/thread; SPLIT->atomicAdd; inline BN ========
// launch_bounds by COG: COG<=8 -> (256,4) 64-reg cap (measured 60); COG=16 -> (256,2).
// CHUNK=2 is the max staging width that does not spill (rounds 8/15/17 evidence).
template<int COG, int MAXCI, bool POOL, bool SPLIT, bool STATS>
__global__ __launch_bounds__(256, (COG<=8) ? 4 : 2) void k_conv32(
    const float* __restrict__ in1, int C1,
    const float* __restrict__ sum1, const float* __restrict__ sq1,
    const float* __restrict__ g1, const float* __restrict__ bb1, float invN1,
    const float* __restrict__ in2, int C2,
    const float* __restrict__ sum2, const float* __restrict__ sq2,
    const float* __restrict__ g2, const float* __restrict__ bb2, float invN2,
    const float* __restrict__ w, const float* __restrict__ bias,
    int Cout, int H, int W, const float* __restrict__ prelu_a, int do_prelu,
    int ciN, int nsplit,
    float* __restrict__ out, float* __restrict__ gsum, float* __restrict__ gsq)
{
    const int Cin = C1 + C2;
    const int tx = threadIdx.x & 15, ty = threadIdx.x >> 4;
    const int nco = Cout / COG;
    int z = blockIdx.z;
    const int sp = z % nsplit; z /= nsplit;
    const int b = z / nco, cob = (z - b*nco)*COG;
    const int ci0 = sp * ciN;
    const int x0 = blockIdx.x*32, y0 = blockIdx.y*32;

    __shared__ float wl[COG*MAXCI*9];
    __shared__ float tile[2][34*36];
    __shared__ float redst[4][2*COG];

    for (int t = threadIdx.x; t < COG*ciN*9; t += 256) {
        int co = t % COG; int rest = t / COG;
        int k = rest % 9; int ci = rest / 9;
        wl[t] = w[(((size_t)(cob+co))*Cin + ci0 + ci)*9 + k];
    }

    float acc[COG][4];
#pragma unroll
    for (int i = 0; i < COG; ++i)
#pragma unroll
        for (int j = 0; j < 4; ++j) acc[i][j] = 0.f;

#pragma unroll 1
    for (int cb = 0; cb < ciN; cb += 2) {
#pragma unroll
        for (int sub = 0; sub < 2; ++sub) {
            int ci = ci0 + cb + sub;
            const float* in; int cc; int Cn;
            const float* sm; const float* sqp; const float* gg; const float* bbp; float iN;
            if (ci < C1) { in = in1; cc = ci;      Cn = C1; sm = sum1; sqp = sq1; gg = g1; bbp = bb1; iN = invN1; }
            else         { in = in2; cc = ci - C1; Cn = C2; sm = sum2; sqp = sq2; gg = g2; bbp = bb2; iN = invN2; }
            float scv = 1.f, shv = 0.f;
            if (sm) bn_ab(sm, sqp, gg, bbp, iN, cc, scv, shv);
            const float* base = in + ((size_t)b*Cn + cc)*H*W;
#pragma unroll 1
            for (int i = threadIdx.x; i < 34*34; i += 256) {
                int r = i / 34, c = i - r*34;
                int gy = y0 - 1 + r, gx = x0 - 1 + c;
                float v = 0.f;
                if ((unsigned)gy < (unsigned)H && (unsigned)gx < (unsigned)W)
                    v = base[(size_t)gy*W + gx]*scv + shv;
                tile[sub][r*36 + c] = v;
            }
        }
        __syncthreads();
#pragma unroll
        for (int sub = 0; sub < 2; ++sub) {
            const float* tl = &tile[sub][(2*ty)*36 + 2*tx];
            float iv[4][4];
#pragma unroll
            for (int r = 0; r < 4; ++r) {
                float2 a2 = *(const float2*)(tl + r*36);
                float2 b2 = *(const float2*)(tl + r*36 + 2);
                iv[r][0]=a2.x; iv[r][1]=a2.y; iv[r][2]=b2.x; iv[r][3]=b2.y;
            }
            const float* wbase = &wl[(cb+sub)*9*COG];
#pragma unroll
            for (int kh = 0; kh < 3; ++kh)
#pragma unroll
            for (int kw = 0; kw < 3; ++kw) {
                const int k = kh*3 + kw;
                float wv[COG];
#pragma unroll
                for (int q = 0; q < COG/4; ++q) {
                    float4 wq = *((const float4*)(wbase + k*COG) + q);
                    wv[4*q+0]=wq.x; wv[4*q+1]=wq.y; wv[4*q+2]=wq.z; wv[4*q+3]=wq.w;
                }
#pragma unroll
                for (int co = 0; co < COG; ++co)
#pragma unroll
                    for (int py = 0; py < 2; ++py)
#pragma unroll
                        for (int px = 0; px < 2; ++px)
                            acc[co][py*2+px] += wv[co]*iv[py+kh][px+kw];
            }
        }
        __syncthreads();
    }

    if (SPLIT) {
        int oy = y0 + 2*ty, ox = x0 + 2*tx;
#pragma unroll
        for (int co = 0; co < COG; ++co) {
            float* op = out + (((size_t)b*Cout + cob + co)*H + oy)*W + ox;
            atomicAdd(&op[0],     acc[co][0]);
            atomicAdd(&op[1],     acc[co][1]);
            atomicAdd(&op[W],     acc[co][2]);
            atomicAdd(&op[W + 1], acc[co][3]);
        }
    } else {
        float a = __ldg(prelu_a);
        float ssum[COG], ssq[COG];
        if (POOL) {
            const int Hp = H >> 1, Wp = W >> 1;
            int pyp = (y0 >> 1) + ty, pxp = (x0 >> 1) + tx;
#pragma unroll
            for (int co = 0; co < COG; ++co) {
                float bv = bias[cob + co];
                float v0 = acc[co][0] + bv, v1 = acc[co][1] + bv;
                float v2 = acc[co][2] + bv, v3 = acc[co][3] + bv;
                v0 = v0 >= 0.f ? v0 : a*v0; v1 = v1 >= 0.f ? v1 : a*v1;
                v2 = v2 >= 0.f ? v2 : a*v2; v3 = v3 >= 0.f ? v3 : a*v3;
                float m = fmaxf(fmaxf(v0,v1), fmaxf(v2,v3));
                out[(((size_t)b*Cout + cob + co)*Hp + pyp)*Wp + pxp] = m;
                ssum[co] = m; ssq[co] = m*m;
            }
            if (STATS) stats_reduceN<COG>(ssum, ssq, redst, cob, gsum, gsq);
        } else {
            int oy = y0 + 2*ty, ox = x0 + 2*tx;
#pragma unroll
            for (int co = 0; co < COG; ++co) {
                float bv = bias[cob + co];
                float* op = out + (((size_t)b*Cout + cob + co)*H + oy)*W + ox;
                float v0 = acc[co][0] + bv, v1 = acc[co][1] + bv;
                float v2 = acc[co][2] + bv, v3 = acc[co][3] + bv;
                if (do_prelu) {
                    v0 = v0 >= 0.f ? v0 : a*v0; v1 = v1 >= 0.f ? v1 : a*v1;
                    v2 = v2 >= 0.f ? v2 : a*v2; v3 = v3 >= 0.f ? v3 : a*v3;
                }
                op[0] = v0; op[1] = v1; op[W] = v2; op[W+1] = v3;
                ssum[co] = v0+v1+v2+v3; ssq[co] = v0*v0+v1*v1+v2*v2+v3*v3;
            }
            if (STATS) stats_reduceN<COG>(ssum, ssq, redst, cob, gsum, gsq);
        }
    }
}

// ---------------- bilinear x2 upsample + opt PReLU + fused per-channel stats ----------------
__global__ __launch_bounds__(256) void k_up2(
    const float* __restrict__ in, float* __restrict__ out, int C, int h, int w,
    const float* __restrict__ prelu_a, int do_prelu,
    float* __restrict__ gsum, float* __restrict__ gsq)
{
    int idx = blockIdx.x*256 + threadIdx.x;
    int W2 = 2*w, H2 = 2*h;
    float a = do_prelu ? __ldg(prelu_a) : 0.f;
    int ox = idx % W2; int t = idx / W2; int oy = t % H2; int bc = t / H2;
    float py = ((float)oy * (float)(h-1)) / (float)(2*h - 1);
    int ly = (int)floorf(py); int hy = min(ly+1, h-1); float fy = py - (float)ly;
    float px = ((float)ox * (float)(w-1)) / (float)(2*w - 1);
    int lx = (int)floorf(px); int hx = min(lx+1, w-1); float fx = px - (float)lx;
    const float* p = in + (size_t)bc*h*w;
    float v00 = p[(size_t)ly*w + lx], v01 = p[(size_t)ly*w + hx];
    float v10 = p[(size_t)hy*w + lx], v11 = p[(size_t)hy*w + hx];
    if (do_prelu) {
        v00 = v00 >= 0.f ? v00 : a*v00;
        v01 = v01 >= 0.f ? v01 : a*v01;
        v10 = v10 >= 0.f ? v10 : a*v10;
        v11 = v11 >= 0.f ? v11 : a*v11;
    }
    float v0 = v00*(1.f-fx) + v01*fx;
    float v1 = v10*(1.f-fx) + v11*fx;
    float v = v0*(1.f-fy) + v1*fy;
    out[idx] = v;
    float s = v, q = v*v;
#pragma unroll
    for (int off = 32; off > 0; off >>= 1) { s += __shfl_down(s, off); q += __shfl_down(q, off); }
    __shared__ float ss[4], qq[4];
    int lane = threadIdx.x & 63, wid = threadIdx.x >> 6;
    if (lane == 0) { ss[wid] = s; qq[wid] = q; }
    __syncthreads();
    if (threadIdx.x == 0) {
        int c = bc % C;
        atomicAdd(&gsum[c], ss[0]+ss[1]+ss[2]+ss[3]);
        atomicAdd(&gsq[c],  qq[0]+qq[1]+qq[2]+qq[3]);
    }
}

// ---------------- final ----------------
__global__ __launch_bounds__(256) void k_final(
    const float* __restrict__ c7, const float* __restrict__ x,
    const float* __restrict__ wbar, const float* __restrict__ bbar,
    float* __restrict__ out)
{
    int idx = blockIdx.x*256 + threadIdx.x;
    if (idx >= 8*65536) return;
    int hw = idx & 65535, b = idx >> 16;
    int oy = hw >> 8, ox = hw & 255;
    float py = ((float)oy * 127.f) / 255.f;
    int ly = (int)floorf(py); int hy = min(ly+1, 127); float fy = py - (float)ly;
    float px = ((float)ox * 127.f) / 255.f;
    int lx = (int)floorf(px); int hx = min(lx+1, 127); float fx = px - (float)lx;
    float w00 = (1.f-fy)*(1.f-fx), w01 = (1.f-fy)*fx, w10 = fy*(1.f-fx), w11v = fy*fx;
    const float* base = c7 + (size_t)b*32*16384;
    float accum = bbar[0];
#pragma unroll 8
    for (int j = 0; j < 32; ++j) {
        const float* p = base + (size_t)j*16384;
        float v = p[ly*128 + lx]*w00 + p[ly*128 + hx]*w01 + p[hy*128 + lx]*w10 + p[hy*128 + hx]*w11v;
        float s = FAST_RCP(1.f + __expf(-v));
        accum += wbar[j]*s;
    }
    size_t xb = (size_t)b*3*65536 + hw;
    float x0 = x[xb], x1 = x[xb + 65536], x2 = x[xb + 2*65536];
    float m = (x0 + x1 + x2)*(1.f/3.f) + 1e-6f;
    float sc = accum * FAST_RCP(m);
    out[xb]            = sc*x0;
    out[xb + 65536]    = sc*x1;
    out[xb + 2*65536]  = sc*x2;
}

extern "C" void kernel_launch(void* const* d_in, const int* in_sizes, int n_in,
                              void* d_out, int out_size, void* d_ws, size_t ws_size,
                              hipStream_t stream) {
    const float* x       = (const float*)d_in[0];
    const float* n16     = (const float*)d_in[1];
    const float* sig16   = (const float*)d_in[2];
    const float* bia16   = (const float*)d_in[3];
    const float* prelu_a = (const float*)d_in[4];
    const float* bn3_g   = (const float*)d_in[5];
    const float* bn3_b   = (const float*)d_in[6];
    const float* bn32_g  = (const float*)d_in[7];
    const float* bn32_b  = (const float*)d_in[8];
    const float* bn64_g  = (const float*)d_in[9];
    const float* bn64_b  = (const float*)d_in[10];
    const float* bn128_g = (const float*)d_in[11];
    const float* bn128_b = (const float*)d_in[12];
    const float* w1 = (const float*)d_in[13]; const float* b1 = (const float*)d_in[14];
    const float* w2 = (const float*)d_in[15]; const float* b2 = (const float*)d_in[16];
    const float* w3 = (const float*)d_in[17]; const float* b3 = (const float*)d_in[18];
    const float* w4 = (const float*)d_in[19]; const float* b4 = (const float*)d_in[20];
    const float* w5 = (const float*)d_in[21]; const float* b5 = (const float*)d_in[22];
    const float* w6 = (const float*)d_in[23]; const float* b6 = (const float*)d_in[24];
    const float* w7 = (const float*)d_in[25]; const float* b7 = (const float*)d_in[26];
    const float* w11= (const float*)d_in[27]; const float* b11= (const float*)d_in[28];
    float* ws  = (float*)d_ws;
    float* out = (float*)d_out;

    (void)hipMemsetAsync(d_ws, 0, 4096*sizeof(float), stream);

    k_branch_stats<<<1536, 256, 0, stream>>>(x, n16, sig16, bia16, ws+S3_SUM, ws+S3_SQ);
    k_prep_all<<<1, 256, 0, stream>>>(ws+S3_SUM, ws+S3_SQ, bn3_g, bn3_b, n16, sig16, bia16,
                                      w11, b11, w1, b1,
                                      ws+W1S_, ws+B1S_, ws+PAD_, ws+SPB_, ws+WBAR_, ws+BBAR_);

    // conv1 v4; grid(8,8,32)=2048
    k_conv1f<8><<<dim3(8,8,32), 256, 0, stream>>>(x, n16, ws+SPB_, ws+W1S_, ws+B1S_, ws+PAD_,
                                                  prelu_a, ws+T1_, ws+S32A_SUM, ws+S32A_SQ);

    // conv2 (32->64 @128) + pool + stats; COG=16 -> T1 re-read 4x; grid(4,4,32)=512
    k_conv32<16,32,true,false,true><<<dim3(4,4,32), 256, 0, stream>>>(
        ws+T1_, 32, ws+S32A_SUM, ws+S32A_SQ, bn32_g, bn32_b, 1.f/131072.f,
        nullptr, 0, nullptr, nullptr, nullptr, nullptr, 0.f,
        w2, b2, 64, 128, 128, prelu_a, 1, 32, 1, ws+T2_, ws+S64A_SUM, ws+S64A_SQ);

    // conv3 (64->128 @64) + pool + stats; inline BN from S64A
    k_conv32<8,64,true,false,true><<<dim3(2,2,128), 256, 0, stream>>>(
        ws+T2_, 64, ws+S64A_SUM, ws+S64A_SQ, bn64_g, bn64_b, 1.f/32768.f,
        nullptr, 0, nullptr, nullptr, nullptr, nullptr, 0.f,
        w3, b3, 128, 64, 64, prelu_a, 1, 64, 1, ws+T3_, ws+S128A_SUM, ws+S128A_SQ);

    // conv4 (128->128 @32), NO prelu; splitK=8 -> 1024 blocks, atomic into b4-filled T4
    k_fill<<<4096, 256, 0, stream>>>(ws+T4_, b4, 128, 1024, 1048576);
    k_conv32<8,16,false,true,false><<<dim3(1,1,1024), 256, 0, stream>>>(
        ws+T3_, 128, ws+S128A_SUM, ws+S128A_SQ, bn128_g, bn128_b, 1.f/8192.f,
        nullptr, 0, nullptr, nullptr, nullptr, nullptr, 0.f,
        w4, nullptr, 128, 32, 32, prelu_a, 0, 16, 8, ws+T4_, nullptr, nullptr);
    k_stats<<<512, 256, 0, stream>>>(ws+T4_, 128, 1024, 4, 2048, ws+S128B_SUM, ws+S128B_SQ);

    // conv5 (concat[x4,x3] 256->64 @32); splitK=16 -> 1024 blocks; prelu deferred to up2
    k_fill<<<2048, 256, 0, stream>>>(ws+C5_, b5, 64, 1024, 524288);
    k_conv32<8,16,false,true,false><<<dim3(1,1,1024), 256, 0, stream>>>(
        ws+T4_, 128, ws+S128B_SUM, ws+S128B_SQ, bn128_g, bn128_b, 1.f/8192.f,
        ws+T3_, 128, ws+S128A_SUM, ws+S128A_SQ, bn128_g, bn128_b, 1.f/8192.f,
        w5, nullptr, 64, 32, 32, prelu_a, 0, 16, 16, ws+C5_, nullptr, nullptr);
    k_up2<<<8192, 256, 0, stream>>>(ws+C5_, ws+U5_, 64, 32, 32, prelu_a, 1, ws+S64B_SUM, ws+S64B_SQ);

    // conv6 (concat[x2,x5] 128->32 @64); splitK=8 -> grid(2,2,256)=1024; prelu deferred
    k_fill<<<4096, 256, 0, stream>>>(ws+C6_, b6, 32, 4096, 1048576);
    k_conv32<8,16,false,true,false><<<dim3(2,2,256), 256, 0, stream>>>(
        ws+T2_, 64, ws+S64A_SUM, ws+S64A_SQ, bn64_g, bn64_b, 1.f/32768.f,
        ws+U5_, 64, ws+S64B_SUM, ws+S64B_SQ, bn64_g, bn64_b, 1.f/32768.f,
        w6, nullptr, 32, 64, 64, prelu_a, 0, 16, 8, ws+C6_, nullptr, nullptr);
    k_up2<<<16384, 256, 0, stream>>>(ws+C6_, ws+U6_, 32, 64, 64, prelu_a, 1, ws+S32B_SUM, ws+S32B_SQ);

    // conv7 (concat[x1,x6] 64->32 @128) + prelu; inline BN from S32A and S32B
    k_conv32<8,64,false,false,false><<<dim3(4,4,32), 256, 0, stream>>>(
        ws+T1_, 32, ws+S32A_SUM, ws+S32A_SQ, bn32_g, bn32_b, 1.f/131072.f,
        ws+U6_, 32, ws+S32B_SUM, ws+S32B_SQ, bn32_g, bn32_b, 1.f/131072.f,
        w7, b7, 32, 128, 128, prelu_a, 1, 64, 1, ws+C7_, nullptr, nullptr);

    k_final<<<2048, 256, 0, stream>>>(ws+C7_, x, ws+WBAR_, ws+BBAR_, out);
}